// Round 4
// baseline (209.742 us; speedup 1.0000x reference)
//
#include <hip/hip_runtime.h>

// Problem constants (reference: H=512, WD=512, K=128)
#define PH 512
#define PWD 512
#define PK 128

// Native clang vector type — __builtin_nontemporal_store requires a real
// vector type, not HIP's float4 class.
typedef float f32x4 __attribute__((ext_vector_type(4)));

// Stage 1: s[d] = sum_c (sum_k x[sx_k, sy_k, c]) * W[c, d]
// One block, 1024 threads (16 waves) so the gather latencies overlap.
__global__ __launch_bounds__(1024)
void compute_s_kernel(const float* __restrict__ x,
                      const float* __restrict__ W,
                      const int* __restrict__ sid,
                      float* __restrict__ s_out) {
    __shared__ float part[8][PK];
    __shared__ float colsum[PK];

    const int tid = threadIdx.x;
    const int c   = tid & (PK - 1);   // 0..127
    const int sub = tid >> 7;         // 0..7

    // Phase 1: partial column sums over k = sub + 8*m  (16 independent loads)
    float p = 0.f;
#pragma unroll
    for (int m = 0; m < 16; ++m) {
        const int k  = sub + (m << 3);
        const int id = sid[k];
        const int sx = id / PH;
        const int sy = id % PWD;
        p += x[(size_t)(sx * PWD + sy) * PK + c];   // coalesced across c
    }
    part[sub][c] = p;
    __syncthreads();

    if (sub == 0) {
        float t = 0.f;
#pragma unroll
        for (int i = 0; i < 8; ++i) t += part[i][c];
        colsum[c] = t;
    }
    __syncthreads();

    // Phase 2: partial s[d=c] over cc = sub + 8*j  (16 independent W loads)
    float q = 0.f;
#pragma unroll
    for (int j = 0; j < 16; ++j) {
        const int cc = sub + (j << 3);
        q = fmaf(colsum[cc], W[cc * PK + c], q);    // W coalesced across c
    }
    part[sub][c] = q;
    __syncthreads();

    if (sub == 0) {
        float t = 0.f;
#pragma unroll
        for (int i = 0; i < 8; ++i) t += part[i][c];
        s_out[c] = t;
    }
}

// Stage 2: broadcast s across all rows. Store-only stream.
// Exact-trip fast path: 524288 threads x 16 float4 stores, fully unrolled,
// nontemporal (L2-bypass) since the data is never re-read.
__global__ __launch_bounds__(256)
void broadcast_kernel(const float* __restrict__ s,
                      f32x4* __restrict__ out,
                      size_t n4) {
    const int tid = threadIdx.x;
    const f32x4* s4 = (const f32x4*)s;
    const f32x4 v = s4[tid & 31];     // thread's d-slot is constant (256 % 32 == 0)

    const size_t stride = (size_t)gridDim.x * blockDim.x;
    const size_t base   = (size_t)blockIdx.x * blockDim.x + tid;

    if (n4 == stride * 16) {
        // Fixed-size fast path: 16 independent unrolled nontemporal stores.
#pragma unroll
        for (int j = 0; j < 16; ++j) {
            __builtin_nontemporal_store(v, &out[base + (size_t)j * stride]);
        }
    } else {
        for (size_t i = base; i < n4; i += stride) {
            __builtin_nontemporal_store(v, &out[i]);
        }
    }
}

extern "C" void kernel_launch(void* const* d_in, const int* in_sizes, int n_in,
                              void* d_out, int out_size, void* d_ws, size_t ws_size,
                              hipStream_t stream) {
    const float* x   = (const float*)d_in[0];   // (512, 512, 128) f32
    const float* W   = (const float*)d_in[1];   // (128, 128) f32
    const int*   sid = (const int*)d_in[2];     // (128,) int32

    float* out  = (float*)d_out;                // (512, 512, 128) f32
    float* s_ws = (float*)d_ws;                 // 128 floats of scratch

    compute_s_kernel<<<1, 1024, 0, stream>>>(x, W, sid, s_ws);

    const size_t n4 = (size_t)out_size / 4;     // 8,388,608
    broadcast_kernel<<<2048, 256, 0, stream>>>(s_ws, (f32x4*)out, n4);
}